// Round 14
// baseline (155.238 us; speedup 1.0000x reference)
//
#include <hip/hip_runtime.h>
#include <hip/hip_cooperative_groups.h>
#include <math.h>

namespace cg = cooperative_groups;

#define NITV 17
#define NCELL (NITV*NITV)        // 289
#define NREP 4
#define QS   4096.0f
#define QINV (1.0/4096.0)
#define CELLF 6
#define AGG_N (NCELL*CELLF)      // 1734
#define PSTRIDE 1760
#define NG 16

// ws dword-offset layout:
#define RAW_OFF   0
#define THR_OFF   4352
#define F2PK_OFF  4384
#define EVT_OFF   4480
#define BVT_OFF   5568
#define ST2_OFF   6656   // stage2 i64[NG][PSTRIDE]
#define PART_OFF  62976  // partials i32[nbh][PSTRIDE]

typedef _Float16 h2 __attribute__((ext_vector_type(2)));

#if __has_builtin(__builtin_amdgcn_fdot2)
__device__ __forceinline__ float fdot2f(h2 a, h2 b, float c) {
  return __builtin_amdgcn_fdot2(a, b, c, false);
}
#else
__device__ __forceinline__ float fdot2f(h2 a, h2 b, float c) {
  return fmaf((float)a.x, (float)b.x, fmaf((float)a.y, (float)b.y, c));
}
#endif

__device__ __forceinline__ int bsearch17(const float* t, float x) {
  bool c8 = t[7] < x;
  float s2 = c8 ? t[11] : t[3];
  bool c4 = s2 < x;
  float sa = c8 ? t[13] : t[5];
  float sb = c8 ? t[9]  : t[1];
  float s3 = c4 ? sa : sb;
  bool c2 = s3 < x;
  float v00 = c2 ? t[2]  : t[0];
  float v01 = c2 ? t[6]  : t[4];
  float v10 = c2 ? t[10] : t[8];
  float v11 = c2 ? t[14] : t[12];
  float w0 = c4 ? v01 : v00;
  float w1 = c4 ? v11 : v10;
  float s4 = c8 ? w1 : w0;
  bool c1 = s4 < x;
  int c = (c8?8:0) + (c4?4:0) + (c2?2:0) + (c1?1:0);
  c += (t[15] < x) ? 1 : 0;
  return c;
}

// ================= phase bodies (shared by coop + fallback) =================

__device__ void do_setup(unsigned char* smem, int tid,
    const float* ehr_w, const float* ehr_b, const float* bio_w, const float* bio_b,
    const float* bio_qkv_w, const float* bio_qkv_b,
    const float* ehr_qkv_w, const float* ehr_qkv_b,
    const float* attn_in_w, const float* attn_in_b,
    const float* attn_out_w, const float* attn_out_b,
    const float* ab_proj_w, const float* ab_proj_b,
    const float* f1_w, const float* f1_b, float* ws)
{
  float* S  = (float*)smem;
  float* M  = S;
  float* P1 = S + 256;
  float* P2 = S + 512;
  float* Ae = S + 768;
  float* Ab = S + 1024;
  float* G  = S + 1280;
  float* Ge = S + 2304;
  float* Gb = S + 3328;
  float* aux  = (float*)(smem + 17408);
  float* mvec = aux;        float* uvec = aux + 16;  float* vvec = aux + 32;
  float* cab  = aux + 48;   float* h0p  = aux + 64;
  float* wEx  = aux + 128;  float* bEx  = aux + 144; float* cEx = aux + 160;
  float* tEx  = aux + 176;  float* wBx  = aux + 192; float* bBx = aux + 208;
  float* cBx  = aux + 224;  float* tBx  = aux + 240;
  int*   rkE  = (int*)(aux + 256);
  int*   rkB  = (int*)(aux + 272);

  {
    int o = tid >> 4, k = tid & 15;
    float s = 0.f;
    for (int j = 0; j < 16; ++j)
      s = fmaf(attn_out_w[o*16+j], attn_in_w[(32+j)*16+k], s);
    M[tid] = s;
  }
  if (tid < 16) {
    float s = attn_out_b[tid];
    for (int j = 0; j < 16; ++j)
      s = fmaf(attn_out_w[tid*16+j], attn_in_b[32+j], s);
    mvec[tid] = s;
  }
  __syncthreads();

  {
    int o = tid >> 4, i = tid & 15;
    float s1 = 0.f, s2 = 0.f;
    for (int t = 0; t < 16; ++t) {
      float mt = M[t*16+i];
      s1 = fmaf(ab_proj_w[o*32+t],    mt, s1);
      s2 = fmaf(ab_proj_w[o*32+16+t], mt, s2);
    }
    P1[tid] = s1; P2[tid] = s2;
  }
  if (tid < 16) {
    float su = mvec[tid], sv = mvec[tid];
    for (int i = 0; i < 16; ++i) {
      float mt = M[tid*16+i];
      su = fmaf(mt, ehr_qkv_b[32+i], su);
      sv = fmaf(mt, bio_qkv_b[32+i], sv);
    }
    uvec[tid] = su; vvec[tid] = sv;
  }
  for (int idx = tid; idx < 1024; idx += 256) {
    int j = idx >> 4, k = idx & 15;
    float s = f1_w[j*32+k];
    for (int i = 0; i < 16; ++i)
      s = fmaf(f1_w[j*32+16+i], M[i*16+k], s);
    G[idx] = s;
  }
  __syncthreads();

  {
    int o = tid >> 4, k = tid & 15;
    float s1 = 0.f, s2 = 0.f;
    for (int i = 0; i < 16; ++i) {
      s1 = fmaf(P1[o*16+i], ehr_qkv_w[(32+i)*16+k], s1);
      s2 = fmaf(P2[o*16+i], bio_qkv_w[(32+i)*16+k], s2);
    }
    Ae[tid] = s1; Ab[tid] = s2;
  }
  if (tid < 16) {
    float s = ab_proj_b[tid];
    for (int t = 0; t < 16; ++t) {
      s = fmaf(ab_proj_w[tid*32+t],    uvec[t], s);
      s = fmaf(ab_proj_w[tid*32+16+t], vvec[t], s);
    }
    cab[tid] = s;
  }
  if (tid < 16) {
    float w = ehr_w[tid], b = ehr_b[tid];
    bool z = (w == 0.0f);
    wEx[tid] = z ? 0.f : w;
    bEx[tid] = z ? 0.f : b;
    cEx[tid] = z ? fmaxf(b, 0.f) : 0.f;
    tEx[tid] = z ? __builtin_inff() : (-b / w);
  } else if (tid < 32) {
    int k = tid - 16;
    float w = bio_w[k], b = bio_b[k];
    bool z = (w == 0.0f);
    wBx[k] = z ? 0.f : w;
    bBx[k] = z ? 0.f : b;
    cBx[k] = z ? fmaxf(b, 0.f) : 0.f;
    tBx[k] = z ? __builtin_inff() : (-b / w);
  }
  __syncthreads();

  for (int idx = tid; idx < 1024; idx += 256) {
    int j = idx >> 4, k = idx & 15;
    float s1 = 0.f, s2 = 0.f;
    for (int i = 0; i < 16; ++i) {
      float g = G[j*16+i];
      s1 = fmaf(g, Ae[i*16+k], s1);
      s2 = fmaf(g, Ab[i*16+k], s2);
    }
    Ge[idx] = s1; Gb[idx] = s2;
  }
  if (tid < 64) {
    float s = f1_b[tid];
    for (int i = 0; i < 16; ++i) {
      s = fmaf(G[tid*16+i], cab[i], s);
      s = fmaf(f1_w[tid*32+16+i], mvec[i], s);
    }
    h0p[tid] = s;
  }
  if (tid < 16) {
    int r = 0;
    for (int j = 0; j < 16; ++j)
      r += (tEx[j] < tEx[tid]) || (tEx[j] == tEx[tid] && j < tid);
    rkE[tid] = r;
  } else if (tid < 32) {
    int k = tid - 16, r = 0;
    for (int j = 0; j < 16; ++j)
      r += (tBx[j] < tBx[k]) || (tBx[j] == tBx[k] && j < k);
    rkB[k] = r;
  }
  __syncthreads();

  if (tid < 64) {
    float s = h0p[tid];
    for (int k = 0; k < 16; ++k)
      s += Ge[tid*16+k]*cEx[k] + Gb[tid*16+k]*cBx[k];
    h0p[tid] = s;
  }
  __syncthreads();

  for (int idx = tid; idx < NITV*64; idx += 256) {
    int i = idx >> 6, j = idx & 63;
    float ue = 0.f, ve = 0.f, ub = 0.f, vb = 0.f;
    for (int k = 0; k < 16; ++k) {
      bool actE = (wEx[k] > 0.f) ? (rkE[k] < i) : (rkE[k] >= i);
      bool actB = (wBx[k] > 0.f) ? (rkB[k] < i) : (rkB[k] >= i);
      if (actE) { ue = fmaf(Ge[j*16+k], wEx[k], ue); ve = fmaf(Ge[j*16+k], bEx[k], ve); }
      if (actB) { ub = fmaf(Gb[j*16+k], wBx[k], ub); vb = fmaf(Gb[j*16+k], bBx[k], vb); }
    }
    ws[RAW_OFF + idx]        = ue;
    ws[RAW_OFF + 1088 + idx] = ve + h0p[j];
    ws[RAW_OFF + 2176 + idx] = ub;
    ws[RAW_OFF + 3264 + idx] = vb;
  }
  if (tid < 16) {
    ws[THR_OFF + rkE[tid]]      = tEx[tid];
    ws[THR_OFF + 16 + rkB[tid]] = tBx[tid];
  }
}

__device__ void do_hist(unsigned char* smem, int tid, int bid, int nbh,
    const float* x, const float* ehr_w, const float* ehr_b,
    const float* bio_w, const float* bio_b,
    int* partials, int B)
{
  int* accS = (int*)smem;                    // NREP*AGG_N ints
  float* thrS = (float*)(smem + 27744);
  if (tid < 16) {
    float tloc[16];
    #pragma unroll
    for (int j = 0; j < 16; ++j) {
      float w = ehr_w[j], b = ehr_b[j];
      tloc[j] = (w == 0.0f) ? __builtin_inff() : (-b / w);
    }
    float mine = tloc[tid];
    int r = 0;
    #pragma unroll
    for (int j = 0; j < 16; ++j)
      r += (tloc[j] < mine) || (tloc[j] == mine && j < tid);
    thrS[r] = mine;
  } else if (tid < 32) {
    int k = tid - 16;
    float tloc[16];
    #pragma unroll
    for (int j = 0; j < 16; ++j) {
      float w = bio_w[j], b = bio_b[j];
      tloc[j] = (w == 0.0f) ? __builtin_inff() : (-b / w);
    }
    float mine = tloc[k];
    int r = 0;
    #pragma unroll
    for (int j = 0; j < 16; ++j)
      r += (tloc[j] < mine) || (tloc[j] == mine && j < k);
    thrS[16 + r] = mine;
  }
  {
    int4 z4 = make_int4(0,0,0,0);
    int4* a4 = (int4*)accS;
    for (int i = tid; i < (NREP*AGG_N)/4; i += 256) a4[i] = z4;
  }
  __syncthreads();

  float te[16], tb[16];
  #pragma unroll
  for (int k = 0; k < 16; ++k) { te[k] = thrS[k]; tb[k] = thrS[16+k]; }
  const int rep = tid & (NREP-1);
  int* const base = &accS[rep*AGG_N];
  const int i4max = (B + 3) >> 2;

  for (int i4 = bid*256 + tid; i4 < i4max; i4 += nbh*256) {
    const int s0 = i4*4;
    float xs0[4], xs2[4];
    int nv = 0;
    if (s0 + 4 <= B) {
      const float4* xp = (const float4*)(x + (size_t)s0*3);
      float4 a = xp[0], b = xp[1], c = xp[2];
      xs0[0]=a.x; xs2[0]=a.z;  xs0[1]=a.w; xs2[1]=b.y;
      xs0[2]=b.z; xs2[2]=c.x;  xs0[3]=c.y; xs2[3]=c.w;
      nv = 4;
    } else {
      for (int u = 0; u < 4; ++u) {
        int i = s0 + u;
        if (i < B) { xs0[nv] = x[3*(size_t)i]; xs2[nv] = x[3*(size_t)i+2]; ++nv; }
      }
    }
    for (int u = 0; u < nv; ++u) {
      float x0 = xs0[u], x2 = xs2[u];
      int iv0 = bsearch17(te, x0);
      int iv2 = bsearch17(tb, x2);
      int* c = base + (iv0*NITV + iv2)*CELLF;
      atomicAdd(c+0, 1);
      atomicAdd(c+1, __float2int_rn(x0*QS));
      atomicAdd(c+2, __float2int_rn(x2*QS));
      atomicAdd(c+3, __float2int_rn(x0*x0*QS));
      atomicAdd(c+4, __float2int_rn(x2*x2*QS));
      atomicAdd(c+5, __float2int_rn(x0*x2*QS));
    }
  }
  __syncthreads();
  int* po = partials + (size_t)bid*PSTRIDE;
  for (int i = tid; i < AGG_N; i += 256)
    po[i] = (accS[i] + accS[AGG_N+i]) + (accS[2*AGG_N+i] + accS[3*AGG_N+i]);
}

__device__ void do_reduce(int bid, int tid, const int* partials,
                          long long* stage2, int nbh)
{
  const int c = bid % 7, g = bid / 7;
  const int f = c*256 + tid;
  if (f >= AGG_N) return;
  long long s = 0;
  for (int b = g; b < nbh; b += NG)
    s += (long long)partials[(size_t)b*PSTRIDE + f];
  stage2[(size_t)g*PSTRIDE + f] = s;
}

__device__ void do_mid(unsigned char* smem, int tid,
    const long long* stage2, float* ws, unsigned int* wsu,
    const float* bn_g, const float* bn_b, const float* f2_w, int B)
{
  float*  aggf = (float*)smem;                 // 1734 f
  float*  Rl   = (float*)(smem + 6944);        // 4352 f
  double* sh2p = (double*)(smem + 24352);      // 256 d
  double* margnE = (double*)(smem + 26400);
  double* margxE = margnE + NITV;
  double* margnB = margxE + NITV;
  double* margxB = margnB + NITV;
  float*  sArr = (float*)(smem + 26944);
  float*  aE   = sArr + 64;
  float*  aB   = sArr + 128;

  for (int i = tid; i < 1088; i += 256)
    ((uint4*)Rl)[i] = ((const uint4*)(ws + RAW_OFF))[i];
  for (int i = tid; i < AGG_N; i += 256) {
    long long v = 0;
    #pragma unroll
    for (int g = 0; g < NG; ++g) v += stage2[(size_t)g*PSTRIDE + i];
    aggf[i] = (i % CELLF == 0) ? (float)v : (float)((double)v * QINV);
  }
  __syncthreads();

  if (tid < NITV) {
    double n = 0, sx = 0;
    for (int q = 0; q < NITV; ++q) {
      n  += (double)aggf[(tid*NITV+q)*CELLF];
      sx += (double)aggf[(tid*NITV+q)*CELLF + 1];
    }
    margnE[tid] = n; margxE[tid] = sx;
  } else if (tid >= 32 && tid < 32+NITV) {
    int q = tid - 32;
    double n = 0, sx = 0;
    for (int p = 0; p < NITV; ++p) {
      n  += (double)aggf[(p*NITV+q)*CELLF];
      sx += (double)aggf[(p*NITV+q)*CELLF + 2];
    }
    margnB[q] = n; margxB[q] = sx;
  }

  {
    const int j = tid & 63, pg = tid >> 6;
    double sh2 = 0;
    for (int p = pg; p < NITV; p += 4) {
      const double Ue = (double)Rl[p*64+j];
      const double Ve = (double)Rl[1088 + p*64+j];
      for (int q = 0; q < NITV; ++q) {
        const float* c = &aggf[(p*NITV+q)*CELLF];
        double n = c[0], sx0 = c[1], sx2 = c[2], s00 = c[3], s22 = c[4], s02 = c[5];
        double Ub = (double)Rl[2176 + q*64+j];
        double Vb = (double)Rl[3264 + q*64+j];
        sh2 += s00*Ue*Ue + 2.0*sx0*Ue*Ve + n*Ve*Ve
             + s22*Ub*Ub + 2.0*sx2*Ub*Vb + n*Vb*Vb
             + 2.0*(s02*Ue*Ub + sx0*Ue*Vb + sx2*Ve*Ub + n*Ve*Vb);
      }
    }
    sh2p[tid] = sh2;
  }
  __syncthreads();

  if (tid < 64) {
    const int j = tid;
    double sh2 = (sh2p[j] + sh2p[64+j]) + (sh2p[128+j] + sh2p[192+j]);
    const double invB = 1.0 / (double)B;
    double mua = 0, mub = 0;
    for (int p = 0; p < NITV; ++p) {
      mua += margxE[p]*(double)Rl[p*64+j]      + margnE[p]*(double)Rl[1088+p*64+j];
      mub += margxB[p]*(double)Rl[2176+p*64+j] + margnB[p]*(double)Rl[3264+p*64+j];
    }
    mua *= invB; mub *= invB;
    double mu  = mua + mub;
    double var = sh2*invB - mu*mu;
    double s   = (double)bn_g[j] / sqrt(var + 1e-5);
    sArr[j] = (float)s;
    aE[j] = (float)(0.5*(double)bn_b[j] - s*mua);
    aB[j] = (float)(0.5*(double)bn_b[j] - s*mub);
  }
  __syncthreads();

  for (int idx = tid; idx < NITV*32; idx += 256) {
    int itv = idx >> 5, p = idx & 31;
    int j0 = 2*p, j1 = 2*p + 1;
    float sc0 = sArr[j0], sc1 = sArr[j1];
    h2 U, V;
    U.x = (_Float16)(sc0 * Rl[itv*64+j0]);
    U.y = (_Float16)(sc1 * Rl[itv*64+j1]);
    V.x = (_Float16)(fmaf(sc0, Rl[1088+itv*64+j0], aE[j0]));
    V.y = (_Float16)(fmaf(sc1, Rl[1088+itv*64+j1], aE[j1]));
    wsu[EVT_OFF + p*34 + 2*itv]     = __builtin_bit_cast(unsigned int, U);
    wsu[EVT_OFF + p*34 + 2*itv + 1] = __builtin_bit_cast(unsigned int, V);
    U.x = (_Float16)(sc0 * Rl[2176+itv*64+j0]);
    U.y = (_Float16)(sc1 * Rl[2176+itv*64+j1]);
    V.x = (_Float16)(fmaf(sc0, Rl[3264+itv*64+j0], aB[j0]));
    V.y = (_Float16)(fmaf(sc1, Rl[3264+itv*64+j1], aB[j1]));
    wsu[BVT_OFF + p*34 + 2*itv]     = __builtin_bit_cast(unsigned int, U);
    wsu[BVT_OFF + p*34 + 2*itv + 1] = __builtin_bit_cast(unsigned int, V);
  }
  if (tid < 96) {
    int c = tid >> 5, p = tid & 31;
    h2 F;
    F.x = (_Float16)f2_w[c*64 + 2*p];
    F.y = (_Float16)f2_w[c*64 + 2*p + 1];
    wsu[F2PK_OFF + tid] = __builtin_bit_cast(unsigned int, F);
  }
}

__device__ void do_apply(unsigned char* smem, int tid, int bid, int nblk,
    const float* x, const float* ws, const unsigned int* wsu,
    const float* f2_b, float* out, int B)
{
  unsigned int* tabs = (unsigned int*)smem;   // 2176 u32
  for (int i = tid; i < 544; i += 256)
    ((uint4*)tabs)[i] = ((const uint4*)(wsu + EVT_OFF))[i];

  float te[16], tb[16];
  #pragma unroll
  for (int k = 0; k < 16; ++k) { te[k] = ws[THR_OFF+k]; tb[k] = ws[THR_OFF+16+k]; }
  const h2* f2h = (const h2*)(wsu + F2PK_OFF);
  const float b0 = f2_b[0], b1 = f2_b[1], b2 = f2_b[2];
  __syncthreads();

  h2 hz; hz.x = (_Float16)0.f; hz.y = (_Float16)0.f;
  const int i4max = (B + 3) >> 2;
  for (int i4 = bid*256 + tid; i4 < i4max; i4 += nblk*256) {
    const int s0 = i4*4;
    float xs0[4], xs2[4];
    int nv = 0;
    if (s0 + 4 <= B) {
      const float4* xp = (const float4*)(x + (size_t)s0*3);
      float4 a = xp[0], b = xp[1], c = xp[2];
      xs0[0]=a.x; xs2[0]=a.z;  xs0[1]=a.w; xs2[1]=b.y;
      xs0[2]=b.z; xs2[2]=c.x;  xs0[3]=c.y; xs2[3]=c.w;
      nv = 4;
    } else {
      for (int u = 0; u < 4; ++u) {
        int i = s0 + u;
        if (i < B) { xs0[nv] = x[3*(size_t)i]; xs2[nv] = x[3*(size_t)i+2]; ++nv; }
      }
    }
    float res[12];
    #pragma unroll
    for (int u = 0; u < 4; ++u) {
      if (u >= nv) break;
      float x0 = xs0[u], x2 = xs2[u];
      int iv0 = bsearch17(te, x0);
      int iv2 = bsearch17(tb, x2);
      const uint2* ev = ((const uint2*)tabs) + iv0;
      const uint2* bv = ((const uint2*)(tabs + 1088)) + iv2;
      h2 x0h; x0h.x = (_Float16)x0; x0h.y = (_Float16)x0;
      h2 x2h; x2h.x = (_Float16)x2; x2h.y = (_Float16)x2;
      float a0 = b0, a1 = b1, a2 = b2;
      #pragma unroll
      for (int p = 0; p < 32; ++p) {
        uint2 e = ev[p*NITV];
        uint2 v = bv[p*NITV];
        h2 hA = __builtin_elementwise_fma(x0h, __builtin_bit_cast(h2, e.x),
                                                __builtin_bit_cast(h2, e.y));
        h2 hB = __builtin_elementwise_fma(x2h, __builtin_bit_cast(h2, v.x),
                                                __builtin_bit_cast(h2, v.y));
        h2 hh = hA + hB;
        h2 r  = __builtin_elementwise_max(hh, hz);
        a0 = fdot2f(r, f2h[p],      a0);
        a1 = fdot2f(r, f2h[32 + p], a1);
        a2 = fdot2f(r, f2h[64 + p], a2);
      }
      res[u*3+0] = a0; res[u*3+1] = a1; res[u*3+2] = a2;
    }
    if (nv == 4) {
      float4* op = (float4*)(out + (size_t)s0*3);
      op[0] = make_float4(res[0], res[1], res[2],  res[3]);
      op[1] = make_float4(res[4], res[5], res[6],  res[7]);
      op[2] = make_float4(res[8], res[9], res[10], res[11]);
    } else {
      for (int u = 0; u < nv; ++u) {
        size_t i = (size_t)(s0 + u);
        out[3*i+0] = res[u*3+0]; out[3*i+1] = res[u*3+1]; out[3*i+2] = res[u*3+2];
      }
    }
  }
}

// ================= cooperative fused kernel =================
__global__ void __launch_bounds__(256, 4) fused_all(
    const float* __restrict__ x,
    const float* __restrict__ ehr_w, const float* __restrict__ ehr_b,
    const float* __restrict__ bio_w, const float* __restrict__ bio_b,
    const float* __restrict__ bio_qkv_w, const float* __restrict__ bio_qkv_b,
    const float* __restrict__ ehr_qkv_w, const float* __restrict__ ehr_qkv_b,
    const float* __restrict__ attn_in_w, const float* __restrict__ attn_in_b,
    const float* __restrict__ attn_out_w, const float* __restrict__ attn_out_b,
    const float* __restrict__ ab_proj_w, const float* __restrict__ ab_proj_b,
    const float* __restrict__ f1_w, const float* __restrict__ f1_b,
    const float* __restrict__ bn_g, const float* __restrict__ bn_b,
    const float* __restrict__ f2_w, const float* __restrict__ f2_b,
    float* __restrict__ ws, float* __restrict__ out, int B, int G)
{
  __shared__ __align__(16) unsigned char smem[27904];
  cg::grid_group grid = cg::this_grid();
  const int tid = threadIdx.x;
  const int bid = (int)blockIdx.x;
  unsigned int* wsu = (unsigned int*)ws;
  int* partials = (int*)ws + PART_OFF;
  long long* stage2 = (long long*)((int*)ws + ST2_OFF);
  const int nbh = G - 1;

  if (bid == nbh)
    do_setup(smem, tid, ehr_w, ehr_b, bio_w, bio_b, bio_qkv_w, bio_qkv_b,
             ehr_qkv_w, ehr_qkv_b, attn_in_w, attn_in_b, attn_out_w, attn_out_b,
             ab_proj_w, ab_proj_b, f1_w, f1_b, ws);
  else
    do_hist(smem, tid, bid, nbh, x, ehr_w, ehr_b, bio_w, bio_b, partials, B);

  grid.sync();

  if (bid < 7*NG) do_reduce(bid, tid, partials, stage2, nbh);

  grid.sync();

  if (bid == 0) do_mid(smem, tid, stage2, ws, wsu, bn_g, bn_b, f2_w, B);

  grid.sync();

  do_apply(smem, tid, bid, G, x, ws, wsu, f2_b, out, B);
}

// ================= fallback kernels (R12-proven pipeline) =================
__global__ void __launch_bounds__(256) hist_kernel(
    const float* __restrict__ x,
    const float* __restrict__ ehr_w, const float* __restrict__ ehr_b,
    const float* __restrict__ bio_w, const float* __restrict__ bio_b,
    const float* __restrict__ bio_qkv_w, const float* __restrict__ bio_qkv_b,
    const float* __restrict__ ehr_qkv_w, const float* __restrict__ ehr_qkv_b,
    const float* __restrict__ attn_in_w, const float* __restrict__ attn_in_b,
    const float* __restrict__ attn_out_w, const float* __restrict__ attn_out_b,
    const float* __restrict__ ab_proj_w, const float* __restrict__ ab_proj_b,
    const float* __restrict__ f1_w, const float* __restrict__ f1_b,
    float* __restrict__ ws, int* __restrict__ partials, int B, int nbh)
{
  __shared__ __align__(16) unsigned char smem[27904];
  const int tid = threadIdx.x;
  if ((int)blockIdx.x == nbh)
    do_setup(smem, tid, ehr_w, ehr_b, bio_w, bio_b, bio_qkv_w, bio_qkv_b,
             ehr_qkv_w, ehr_qkv_b, attn_in_w, attn_in_b, attn_out_w, attn_out_b,
             ab_proj_w, ab_proj_b, f1_w, f1_b, ws);
  else
    do_hist(smem, tid, (int)blockIdx.x, nbh, x, ehr_w, ehr_b, bio_w, bio_b,
            partials, B);
}

__global__ void __launch_bounds__(256) reduce_kernel(
    const int* __restrict__ partials, long long* __restrict__ stage2, int nbh)
{
  do_reduce((int)blockIdx.x, threadIdx.x, partials, stage2, nbh);
}

__global__ void __launch_bounds__(256) mid_kernel(
    const long long* __restrict__ stage2, float* ws, unsigned int* wsu,
    const float* __restrict__ bn_g, const float* __restrict__ bn_b,
    const float* __restrict__ f2_w, int B)
{
  __shared__ __align__(16) unsigned char smem[27744];
  do_mid(smem, threadIdx.x, stage2, ws, wsu, bn_g, bn_b, f2_w, B);
}

__global__ void __launch_bounds__(256) apply_kernel(
    const float* __restrict__ x, const float* __restrict__ ws,
    const unsigned int* __restrict__ wsu, const float* __restrict__ f2_b,
    float* __restrict__ out, int B, int nblk)
{
  __shared__ __align__(16) unsigned char smem[8704];
  do_apply(smem, threadIdx.x, (int)blockIdx.x, nblk, x, ws, wsu, f2_b, out, B);
}

extern "C" void kernel_launch(void* const* d_in, const int* in_sizes, int n_in,
                              void* d_out, int out_size, void* d_ws, size_t ws_size,
                              hipStream_t stream) {
  const float* x          = (const float*)d_in[0];
  const float* ehr_w      = (const float*)d_in[1];
  const float* ehr_b      = (const float*)d_in[2];
  const float* bio_w      = (const float*)d_in[5];
  const float* bio_b      = (const float*)d_in[6];
  const float* bio_qkv_w  = (const float*)d_in[7];
  const float* bio_qkv_b  = (const float*)d_in[8];
  const float* ehr_qkv_w  = (const float*)d_in[9];
  const float* ehr_qkv_b  = (const float*)d_in[10];
  const float* attn_in_w  = (const float*)d_in[13];
  const float* attn_in_b  = (const float*)d_in[14];
  const float* attn_out_w = (const float*)d_in[15];
  const float* attn_out_b = (const float*)d_in[16];
  const float* ab_proj_w  = (const float*)d_in[17];
  const float* ab_proj_b  = (const float*)d_in[18];
  const float* f1_w       = (const float*)d_in[19];
  const float* f1_b       = (const float*)d_in[20];
  const float* bn_g       = (const float*)d_in[21];
  const float* bn_b       = (const float*)d_in[22];
  const float* f2_w       = (const float*)d_in[23];
  const float* f2_b       = (const float*)d_in[24];
  float* out = (float*)d_out;
  float* ws  = (float*)d_ws;
  unsigned int* wsu = (unsigned int*)d_ws;
  int* partials = (int*)d_ws + PART_OFF;
  long long* stage2 = (long long*)((int*)d_ws + ST2_OFF);
  int B = in_sizes[0] / 3;

  // workspace capacity for partial rows
  long long avail = (long long)(ws_size / 4) - PART_OFF;
  int cap = (int)(avail / PSTRIDE);
  if (cap > 1023) cap = 1023;

  // ---- try cooperative fused launch with runtime-validated grid ----
  int nbPerCU = 0;
  hipError_t qe = hipOccupancyMaxActiveBlocksPerMultiprocessor(
      &nbPerCU, (const void*)fused_all, 256, 0);
  int G = (qe == hipSuccess) ? nbPerCU * 256 : 0;
  if (G > 1024) G = 1024;
  if (G - 1 > cap) G = cap + 1;

  hipError_t e = hipErrorUnknown;
  if (G >= 160) {
    void* args[] = {
      (void*)&x,
      (void*)&ehr_w, (void*)&ehr_b, (void*)&bio_w, (void*)&bio_b,
      (void*)&bio_qkv_w, (void*)&bio_qkv_b, (void*)&ehr_qkv_w, (void*)&ehr_qkv_b,
      (void*)&attn_in_w, (void*)&attn_in_b, (void*)&attn_out_w, (void*)&attn_out_b,
      (void*)&ab_proj_w, (void*)&ab_proj_b, (void*)&f1_w, (void*)&f1_b,
      (void*)&bn_g, (void*)&bn_b, (void*)&f2_w, (void*)&f2_b,
      (void*)&ws, (void*)&out, (void*)&B, (void*)&G
    };
    e = hipLaunchCooperativeKernel((const void*)fused_all, dim3(G), dim3(256),
                                   args, 0, stream);
  }
  if (e != hipSuccess) {
    // ---- fallback: proven 4-kernel pipeline ----
    int nbh = cap;
    if (nbh > 1023) nbh = 1023;
    if (nbh < 128)  nbh = 128;
    hist_kernel<<<nbh+1, 256, 0, stream>>>(x, ehr_w, ehr_b, bio_w, bio_b,
        bio_qkv_w, bio_qkv_b, ehr_qkv_w, ehr_qkv_b,
        attn_in_w, attn_in_b, attn_out_w, attn_out_b,
        ab_proj_w, ab_proj_b, f1_w, f1_b, ws, partials, B, nbh);
    reduce_kernel<<<7*NG, 256, 0, stream>>>(partials, stage2, nbh);
    mid_kernel<<<1, 256, 0, stream>>>(stage2, ws, wsu, bn_g, bn_b, f2_w, B);
    int nblk = (B + 1023) / 1024;
    apply_kernel<<<nblk, 256, 0, stream>>>(x, ws, wsu, f2_b, out, B, nblk);
  }
}

// Round 16
// 72.130 us; speedup vs baseline: 2.1522x; 2.1522x over previous
//
#include <hip/hip_runtime.h>
#include <math.h>

#define NITV 17
#define NCELL (NITV*NITV)        // 289
#define NREP 6                   // hist LDS replicas (i32); 41.6KB -> 3 blocks/CU
#define QS   4096.0f
#define QINV (1.0/4096.0)
#define CELLF 6
#define AGG_N (NCELL*CELLF)      // 1734
#define PSTRIDE 1760
#define NG 16
#define NBH_MAX 768              // 3 blocks/CU * 256 CU

// ws dword-offset layout:
#define RAW_OFF   0
#define THR_OFF   4352
#define F2PK_OFF  4384
#define EVT_OFF   4480
#define BVT_OFF   5568
#define ST2_OFF   6656   // stage2 i64[NG][PSTRIDE]
#define PART_OFF  62976  // partials i32[nbh][PSTRIDE]

typedef _Float16 h2 __attribute__((ext_vector_type(2)));

#if __has_builtin(__builtin_amdgcn_fdot2)
__device__ __forceinline__ float fdot2f(h2 a, h2 b, float c) {
  return __builtin_amdgcn_fdot2(a, b, c, false);
}
#else
__device__ __forceinline__ float fdot2f(h2 a, h2 b, float c) {
  return fmaf((float)a.x, (float)b.x, fmaf((float)a.y, (float)b.y, c));
}
#endif

// count of sorted t[0..15] strictly less than x (17 outcomes; t[15] fix-up).
__device__ __forceinline__ int bsearch17(const float* t, float x) {
  bool c8 = t[7] < x;
  float s2 = c8 ? t[11] : t[3];
  bool c4 = s2 < x;
  float sa = c8 ? t[13] : t[5];
  float sb = c8 ? t[9]  : t[1];
  float s3 = c4 ? sa : sb;
  bool c2 = s3 < x;
  float v00 = c2 ? t[2]  : t[0];
  float v01 = c2 ? t[6]  : t[4];
  float v10 = c2 ? t[10] : t[8];
  float v11 = c2 ? t[14] : t[12];
  float w0 = c4 ? v01 : v00;
  float w1 = c4 ? v11 : v10;
  float s4 = c8 ? w1 : w0;
  bool c1 = s4 < x;
  int c = (c8?8:0) + (c4?4:0) + (c2?2:0) + (c1?1:0);
  c += (t[15] < x) ? 1 : 0;
  return c;
}

// ------------- Kernel 1: 6x i32 LDS-atomic histogram (NREP=6) + setup block -------------
__global__ void __launch_bounds__(256) hist_kernel(
    const float* __restrict__ x,
    const float* __restrict__ ehr_w, const float* __restrict__ ehr_b,
    const float* __restrict__ bio_w, const float* __restrict__ bio_b,
    const float* __restrict__ bio_qkv_w, const float* __restrict__ bio_qkv_b,
    const float* __restrict__ ehr_qkv_w, const float* __restrict__ ehr_qkv_b,
    const float* __restrict__ attn_in_w, const float* __restrict__ attn_in_b,
    const float* __restrict__ attn_out_w, const float* __restrict__ attn_out_b,
    const float* __restrict__ ab_proj_w, const float* __restrict__ ab_proj_b,
    const float* __restrict__ f1_w, const float* __restrict__ f1_b,
    float* __restrict__ ws, int* __restrict__ partials,
    int B, int nbh)
{
  __shared__ __align__(16) int accS[NREP*AGG_N];   // 41.6 KB; setup reuses as float scratch
  __shared__ float thrS[32];
  __shared__ float mvec[16], uvec[16], vvec[16], cab[16], h0p[64];
  __shared__ float wEx[16], bEx[16], cEx[16], tEx[16];
  __shared__ float wBx[16], bBx[16], cBx[16], tBx[16];
  __shared__ int   rkE[16], rkB[16];
  const int tid = threadIdx.x;

  if ((int)blockIdx.x == nbh) {
    // ---------------- setup-only block: build raw tables once ----------------
    float* S  = (float*)accS;       // needs 4352 floats <= 10404 available
    float* M  = S;
    float* P1 = S + 256;
    float* P2 = S + 512;
    float* Ae = S + 768;
    float* Ab = S + 1024;
    float* G  = S + 1280;
    float* Ge = S + 2304;
    float* Gb = S + 3328;

    {
      int o = tid >> 4, k = tid & 15;
      float s = 0.f;
      for (int j = 0; j < 16; ++j)
        s = fmaf(attn_out_w[o*16+j], attn_in_w[(32+j)*16+k], s);
      M[tid] = s;
    }
    if (tid < 16) {
      float s = attn_out_b[tid];
      for (int j = 0; j < 16; ++j)
        s = fmaf(attn_out_w[tid*16+j], attn_in_b[32+j], s);
      mvec[tid] = s;
    }
    __syncthreads();

    {
      int o = tid >> 4, i = tid & 15;
      float s1 = 0.f, s2 = 0.f;
      for (int t = 0; t < 16; ++t) {
        float mt = M[t*16+i];
        s1 = fmaf(ab_proj_w[o*32+t],    mt, s1);
        s2 = fmaf(ab_proj_w[o*32+16+t], mt, s2);
      }
      P1[tid] = s1; P2[tid] = s2;
    }
    if (tid < 16) {
      float su = mvec[tid], sv = mvec[tid];
      for (int i = 0; i < 16; ++i) {
        float mt = M[tid*16+i];
        su = fmaf(mt, ehr_qkv_b[32+i], su);
        sv = fmaf(mt, bio_qkv_b[32+i], sv);
      }
      uvec[tid] = su; vvec[tid] = sv;
    }
    for (int idx = tid; idx < 1024; idx += 256) {
      int j = idx >> 4, k = idx & 15;
      float s = f1_w[j*32+k];
      for (int i = 0; i < 16; ++i)
        s = fmaf(f1_w[j*32+16+i], M[i*16+k], s);
      G[idx] = s;
    }
    __syncthreads();

    {
      int o = tid >> 4, k = tid & 15;
      float s1 = 0.f, s2 = 0.f;
      for (int i = 0; i < 16; ++i) {
        s1 = fmaf(P1[o*16+i], ehr_qkv_w[(32+i)*16+k], s1);
        s2 = fmaf(P2[o*16+i], bio_qkv_w[(32+i)*16+k], s2);
      }
      Ae[tid] = s1; Ab[tid] = s2;
    }
    if (tid < 16) {
      float s = ab_proj_b[tid];
      for (int t = 0; t < 16; ++t) {
        s = fmaf(ab_proj_w[tid*32+t],    uvec[t], s);
        s = fmaf(ab_proj_w[tid*32+16+t], vvec[t], s);
      }
      cab[tid] = s;
    }
    if (tid < 16) {
      float w = ehr_w[tid], b = ehr_b[tid];
      bool z = (w == 0.0f);
      wEx[tid] = z ? 0.f : w;
      bEx[tid] = z ? 0.f : b;
      cEx[tid] = z ? fmaxf(b, 0.f) : 0.f;
      tEx[tid] = z ? __builtin_inff() : (-b / w);
    } else if (tid < 32) {
      int k = tid - 16;
      float w = bio_w[k], b = bio_b[k];
      bool z = (w == 0.0f);
      wBx[k] = z ? 0.f : w;
      bBx[k] = z ? 0.f : b;
      cBx[k] = z ? fmaxf(b, 0.f) : 0.f;
      tBx[k] = z ? __builtin_inff() : (-b / w);
    }
    __syncthreads();

    for (int idx = tid; idx < 1024; idx += 256) {
      int j = idx >> 4, k = idx & 15;
      float s1 = 0.f, s2 = 0.f;
      for (int i = 0; i < 16; ++i) {
        float g = G[j*16+i];
        s1 = fmaf(g, Ae[i*16+k], s1);
        s2 = fmaf(g, Ab[i*16+k], s2);
      }
      Ge[idx] = s1; Gb[idx] = s2;
    }
    if (tid < 64) {
      float s = f1_b[tid];
      for (int i = 0; i < 16; ++i) {
        s = fmaf(G[tid*16+i], cab[i], s);
        s = fmaf(f1_w[tid*32+16+i], mvec[i], s);
      }
      h0p[tid] = s;
    }
    if (tid < 16) {
      int r = 0;
      for (int j = 0; j < 16; ++j)
        r += (tEx[j] < tEx[tid]) || (tEx[j] == tEx[tid] && j < tid);
      rkE[tid] = r;
    } else if (tid < 32) {
      int k = tid - 16, r = 0;
      for (int j = 0; j < 16; ++j)
        r += (tBx[j] < tBx[k]) || (tBx[j] == tBx[k] && j < k);
      rkB[k] = r;
    }
    __syncthreads();

    if (tid < 64) {
      float s = h0p[tid];
      for (int k = 0; k < 16; ++k)
        s += Ge[tid*16+k]*cEx[k] + Gb[tid*16+k]*cBx[k];
      h0p[tid] = s;
    }
    __syncthreads();

    for (int idx = tid; idx < NITV*64; idx += 256) {
      int i = idx >> 6, j = idx & 63;
      float ue = 0.f, ve = 0.f, ub = 0.f, vb = 0.f;
      for (int k = 0; k < 16; ++k) {
        bool actE = (wEx[k] > 0.f) ? (rkE[k] < i) : (rkE[k] >= i);
        bool actB = (wBx[k] > 0.f) ? (rkB[k] < i) : (rkB[k] >= i);
        if (actE) { ue = fmaf(Ge[j*16+k], wEx[k], ue); ve = fmaf(Ge[j*16+k], bEx[k], ve); }
        if (actB) { ub = fmaf(Gb[j*16+k], wBx[k], ub); vb = fmaf(Gb[j*16+k], bBx[k], vb); }
      }
      ws[RAW_OFF + idx]        = ue;
      ws[RAW_OFF + 1088 + idx] = ve + h0p[j];
      ws[RAW_OFF + 2176 + idx] = ub;
      ws[RAW_OFF + 3264 + idx] = vb;
    }
    if (tid < 16) {
      ws[THR_OFF + rkE[tid]]      = tEx[tid];
      ws[THR_OFF + 16 + rkB[tid]] = tBx[tid];
    }
    return;
  }

  // ---------------- histogram path ----------------
  if (tid < 16) {
    float tloc[16];
    #pragma unroll
    for (int j = 0; j < 16; ++j) {
      float w = ehr_w[j], b = ehr_b[j];
      tloc[j] = (w == 0.0f) ? __builtin_inff() : (-b / w);
    }
    float mine = tloc[tid];
    int r = 0;
    #pragma unroll
    for (int j = 0; j < 16; ++j)
      r += (tloc[j] < mine) || (tloc[j] == mine && j < tid);
    thrS[r] = mine;
  } else if (tid < 32) {
    int k = tid - 16;
    float tloc[16];
    #pragma unroll
    for (int j = 0; j < 16; ++j) {
      float w = bio_w[j], b = bio_b[j];
      tloc[j] = (w == 0.0f) ? __builtin_inff() : (-b / w);
    }
    float mine = tloc[k];
    int r = 0;
    #pragma unroll
    for (int j = 0; j < 16; ++j)
      r += (tloc[j] < mine) || (tloc[j] == mine && j < k);
    thrS[16 + r] = mine;
  }
  {
    int4 z4 = make_int4(0,0,0,0);
    int4* a4 = (int4*)accS;
    for (int i = tid; i < (NREP*AGG_N)/4; i += 256) a4[i] = z4;  // 10404/4 = 2601
  }
  __syncthreads();

  float te[16], tb[16];
  #pragma unroll
  for (int k = 0; k < 16; ++k) { te[k] = thrS[k]; tb[k] = thrS[16+k]; }
  const int rep = tid % NREP;
  int* const base = &accS[rep*AGG_N];
  const int i4max = (B + 3) >> 2;

  for (int i4 = blockIdx.x*256 + tid; i4 < i4max; i4 += nbh*256) {
    const int s0 = i4*4;
    float xs0[4], xs2[4];
    int nv = 0;
    if (s0 + 4 <= B) {
      const float4* xp = (const float4*)(x + (size_t)s0*3);
      float4 a = xp[0], b = xp[1], c = xp[2];
      xs0[0]=a.x; xs2[0]=a.z;  xs0[1]=a.w; xs2[1]=b.y;
      xs0[2]=b.z; xs2[2]=c.x;  xs0[3]=c.y; xs2[3]=c.w;
      nv = 4;
    } else {
      for (int u = 0; u < 4; ++u) {
        int i = s0 + u;
        if (i < B) { xs0[nv] = x[3*(size_t)i]; xs2[nv] = x[3*(size_t)i+2]; ++nv; }
      }
    }
    for (int u = 0; u < nv; ++u) {
      float x0 = xs0[u], x2 = xs2[u];
      int iv0 = bsearch17(te, x0);
      int iv2 = bsearch17(tb, x2);
      int* c = base + (iv0*NITV + iv2)*CELLF;
      atomicAdd(c+0, 1);
      atomicAdd(c+1, __float2int_rn(x0*QS));
      atomicAdd(c+2, __float2int_rn(x2*QS));
      atomicAdd(c+3, __float2int_rn(x0*x0*QS));
      atomicAdd(c+4, __float2int_rn(x2*x2*QS));
      atomicAdd(c+5, __float2int_rn(x0*x2*QS));
    }
  }
  __syncthreads();
  // per-block partial: plain coalesced store, no global atomics
  int* out = partials + (size_t)blockIdx.x*PSTRIDE;
  for (int i = tid; i < AGG_N; i += 256) {
    int s = 0;
    #pragma unroll
    for (int r = 0; r < NREP; ++r) s += accS[r*AGG_N + i];
    out[i] = s;
  }
}

// ------------- Kernel 1b: deterministic tree reduce: partials -> stage2 i64 -------------
__global__ void __launch_bounds__(256) reduce_kernel(
    const int* __restrict__ partials, long long* __restrict__ stage2, int nbh)
{
  const int c = blockIdx.x % 7, g = blockIdx.x / 7;
  const int f = c*256 + threadIdx.x;
  if (f >= AGG_N) { if (f < PSTRIDE) stage2[(size_t)g*PSTRIDE + f] = 0; return; }
  long long s = 0;
  for (int b = g; b < nbh; b += NG)          // fixed order per g -> deterministic
    s += (long long)partials[(size_t)b*PSTRIDE + f];
  stage2[(size_t)g*PSTRIDE + f] = s;
}

// ------------- Kernel 2: finalize once -> scaled fp16-packed transposed tables -------------
__global__ void __launch_bounds__(256) mid_kernel(
    const long long* __restrict__ stage2,
    float* ws, unsigned int* wsu,
    const float* __restrict__ bn_g, const float* __restrict__ bn_b,
    const float* __restrict__ f2_w, int B)
{
  __shared__ double aggd[AGG_N];               // 13.9 KB
  __shared__ float  Rl[4352];                  // 17.4 KB
  __shared__ double sh2p[256];                 // 2 KB
  __shared__ double margnE[NITV], margxE[NITV], margnB[NITV], margxB[NITV];
  __shared__ float  sArr[64], aE[64], aB[64];
  const int tid = threadIdx.x;

  for (int i = tid; i < 1088; i += 256)
    ((uint4*)Rl)[i] = ((const uint4*)(ws + RAW_OFF))[i];
  for (int i = tid; i < AGG_N; i += 256) {
    long long v = 0;
    #pragma unroll
    for (int g = 0; g < NG; ++g) v += stage2[(size_t)g*PSTRIDE + i];
    aggd[i] = (i % CELLF == 0) ? (double)v : (double)v * QINV;
  }
  __syncthreads();

  // marginals from joint
  if (tid < NITV) {
    double n = 0, sx = 0;
    for (int q = 0; q < NITV; ++q) {
      n  += aggd[(tid*NITV+q)*CELLF];
      sx += aggd[(tid*NITV+q)*CELLF + 1];
    }
    margnE[tid] = n; margxE[tid] = sx;
  } else if (tid >= 32 && tid < 32+NITV) {
    int q = tid - 32;
    double n = 0, sx = 0;
    for (int p = 0; p < NITV; ++p) {
      n  += aggd[(p*NITV+q)*CELLF];
      sx += aggd[(p*NITV+q)*CELLF + 2];
    }
    margnB[q] = n; margxB[q] = sx;
  }

  // E[h^2]*B, striped over p by 4 wave-groups
  {
    const int j = tid & 63, pg = tid >> 6;
    double sh2 = 0;
    for (int p = pg; p < NITV; p += 4) {
      const double Ue = (double)Rl[p*64+j];
      const double Ve = (double)Rl[1088 + p*64+j];
      for (int q = 0; q < NITV; ++q) {
        const double* c = &aggd[(p*NITV+q)*CELLF];
        double n = c[0], sx0 = c[1], sx2 = c[2], s00 = c[3], s22 = c[4], s02 = c[5];
        double Ub = (double)Rl[2176 + q*64+j];
        double Vb = (double)Rl[3264 + q*64+j];
        sh2 += s00*Ue*Ue + 2.0*sx0*Ue*Ve + n*Ve*Ve
             + s22*Ub*Ub + 2.0*sx2*Ub*Vb + n*Vb*Vb
             + 2.0*(s02*Ue*Ub + sx0*Ue*Vb + sx2*Ve*Ub + n*Ve*Vb);
      }
    }
    sh2p[tid] = sh2;
  }
  __syncthreads();

  if (tid < 64) {
    const int j = tid;
    double sh2 = (sh2p[j] + sh2p[64+j]) + (sh2p[128+j] + sh2p[192+j]);
    const double invB = 1.0 / (double)B;
    double mua = 0, mub = 0;
    for (int p = 0; p < NITV; ++p) {
      mua += margxE[p]*(double)Rl[p*64+j]      + margnE[p]*(double)Rl[1088+p*64+j];
      mub += margxB[p]*(double)Rl[2176+p*64+j] + margnB[p]*(double)Rl[3264+p*64+j];
    }
    mua *= invB; mub *= invB;
    double mu  = mua + mub;
    double var = sh2*invB - mu*mu;
    double s   = (double)bn_g[j] / sqrt(var + 1e-5);
    sArr[j] = (float)s;
    aE[j] = (float)(0.5*(double)bn_b[j] - s*mua);   // split centers keep V small for fp16
    aB[j] = (float)(0.5*(double)bn_b[j] - s*mub);
  }
  __syncthreads();

  // pack scaled fp16 tables, transposed [pair p][itv] as (U half2, V half2)
  for (int idx = tid; idx < NITV*32; idx += 256) {
    int itv = idx >> 5, p = idx & 31;
    int j0 = 2*p, j1 = 2*p + 1;
    float sc0 = sArr[j0], sc1 = sArr[j1];
    h2 U, V;
    U.x = (_Float16)(sc0 * Rl[itv*64+j0]);
    U.y = (_Float16)(sc1 * Rl[itv*64+j1]);
    V.x = (_Float16)(fmaf(sc0, Rl[1088+itv*64+j0], aE[j0]));
    V.y = (_Float16)(fmaf(sc1, Rl[1088+itv*64+j1], aE[j1]));
    wsu[EVT_OFF + p*34 + 2*itv]     = __builtin_bit_cast(unsigned int, U);
    wsu[EVT_OFF + p*34 + 2*itv + 1] = __builtin_bit_cast(unsigned int, V);
    U.x = (_Float16)(sc0 * Rl[2176+itv*64+j0]);
    U.y = (_Float16)(sc1 * Rl[2176+itv*64+j1]);
    V.x = (_Float16)(fmaf(sc0, Rl[3264+itv*64+j0], aB[j0]));
    V.y = (_Float16)(fmaf(sc1, Rl[3264+itv*64+j1], aB[j1]));
    wsu[BVT_OFF + p*34 + 2*itv]     = __builtin_bit_cast(unsigned int, U);
    wsu[BVT_OFF + p*34 + 2*itv + 1] = __builtin_bit_cast(unsigned int, V);
  }
  if (tid < 96) {
    int c = tid >> 5, p = tid & 31;
    h2 F;
    F.x = (_Float16)f2_w[c*64 + 2*p];
    F.y = (_Float16)f2_w[c*64 + 2*p + 1];
    wsu[F2PK_OFF + tid] = __builtin_bit_cast(unsigned int, F);
  }
}

// ------------- Kernel 3: apply (fp16 packed, conflict-free transposed reads) -------------
__global__ void __launch_bounds__(256) apply_kernel(
    const float* __restrict__ x, const float* __restrict__ ws,
    const unsigned int* __restrict__ wsu,
    const float* __restrict__ f2_b,
    float* __restrict__ out, int B)
{
  __shared__ __align__(16) unsigned int tabs[2176];   // EVT [0..1088), BVT [1088..2176)
  const int tid = threadIdx.x;

  const int s0 = (blockIdx.x*256 + tid)*4;
  float xs0[4], xs2[4];
  int nv = 0;
  if (s0 + 4 <= B) {
    const float4* xp = (const float4*)(x + (size_t)s0*3);
    float4 a = xp[0], b = xp[1], c = xp[2];
    xs0[0]=a.x; xs2[0]=a.z;  xs0[1]=a.w; xs2[1]=b.y;
    xs0[2]=b.z; xs2[2]=c.x;  xs0[3]=c.y; xs2[3]=c.w;
    nv = 4;
  } else {
    for (int u = 0; u < 4; ++u) {
      int i = s0 + u;
      if (i < B) { xs0[nv] = x[3*(size_t)i]; xs2[nv] = x[3*(size_t)i+2]; ++nv; }
    }
  }

  for (int i = tid; i < 544; i += 256)
    ((uint4*)tabs)[i] = ((const uint4*)(wsu + EVT_OFF))[i];

  float te[16], tb[16];
  #pragma unroll
  for (int k = 0; k < 16; ++k) { te[k] = ws[THR_OFF+k]; tb[k] = ws[THR_OFF+16+k]; }
  const h2* f2h = (const h2*)(wsu + F2PK_OFF);
  const float b0 = f2_b[0], b1 = f2_b[1], b2 = f2_b[2];
  __syncthreads();

  h2 hz; hz.x = (_Float16)0.f; hz.y = (_Float16)0.f;
  float res[12];
  #pragma unroll
  for (int u = 0; u < 4; ++u) {
    if (u >= nv) break;
    float x0 = xs0[u], x2 = xs2[u];
    int iv0 = bsearch17(te, x0);
    int iv2 = bsearch17(tb, x2);
    const uint2* ev = ((const uint2*)tabs) + iv0;          // + p*17
    const uint2* bv = ((const uint2*)(tabs + 1088)) + iv2;
    h2 x0h; x0h.x = (_Float16)x0; x0h.y = (_Float16)x0;
    h2 x2h; x2h.x = (_Float16)x2; x2h.y = (_Float16)x2;
    float a0 = b0, a1 = b1, a2 = b2;
    #pragma unroll
    for (int p = 0; p < 32; ++p) {
      uint2 e = ev[p*NITV];
      uint2 v = bv[p*NITV];
      h2 hA = __builtin_elementwise_fma(x0h, __builtin_bit_cast(h2, e.x),
                                              __builtin_bit_cast(h2, e.y));
      h2 hB = __builtin_elementwise_fma(x2h, __builtin_bit_cast(h2, v.x),
                                              __builtin_bit_cast(h2, v.y));
      h2 hh = hA + hB;
      h2 r  = __builtin_elementwise_max(hh, hz);
      a0 = fdot2f(r, f2h[p],      a0);
      a1 = fdot2f(r, f2h[32 + p], a1);
      a2 = fdot2f(r, f2h[64 + p], a2);
    }
    res[u*3+0] = a0; res[u*3+1] = a1; res[u*3+2] = a2;
  }
  if (nv == 4) {
    float4* op = (float4*)(out + (size_t)s0*3);
    op[0] = make_float4(res[0], res[1], res[2],  res[3]);
    op[1] = make_float4(res[4], res[5], res[6],  res[7]);
    op[2] = make_float4(res[8], res[9], res[10], res[11]);
  } else {
    for (int u = 0; u < nv; ++u) {
      size_t i = (size_t)(s0 + u);
      out[3*i+0] = res[u*3+0]; out[3*i+1] = res[u*3+1]; out[3*i+2] = res[u*3+2];
    }
  }
}

extern "C" void kernel_launch(void* const* d_in, const int* in_sizes, int n_in,
                              void* d_out, int out_size, void* d_ws, size_t ws_size,
                              hipStream_t stream) {
  const float* x          = (const float*)d_in[0];
  const float* ehr_w      = (const float*)d_in[1];
  const float* ehr_b      = (const float*)d_in[2];
  const float* bio_w      = (const float*)d_in[5];
  const float* bio_b      = (const float*)d_in[6];
  const float* bio_qkv_w  = (const float*)d_in[7];
  const float* bio_qkv_b  = (const float*)d_in[8];
  const float* ehr_qkv_w  = (const float*)d_in[9];
  const float* ehr_qkv_b  = (const float*)d_in[10];
  const float* attn_in_w  = (const float*)d_in[13];
  const float* attn_in_b  = (const float*)d_in[14];
  const float* attn_out_w = (const float*)d_in[15];
  const float* attn_out_b = (const float*)d_in[16];
  const float* ab_proj_w  = (const float*)d_in[17];
  const float* ab_proj_b  = (const float*)d_in[18];
  const float* f1_w       = (const float*)d_in[19];
  const float* f1_b       = (const float*)d_in[20];
  const float* bn_g       = (const float*)d_in[21];
  const float* bn_b       = (const float*)d_in[22];
  const float* f2_w       = (const float*)d_in[23];
  const float* f2_b       = (const float*)d_in[24];
  float* out = (float*)d_out;
  float* ws  = (float*)d_ws;
  unsigned int* wsu = (unsigned int*)d_ws;
  int* partials = (int*)d_ws + PART_OFF;
  long long* stage2 = (long long*)((int*)d_ws + ST2_OFF);
  const int B = in_sizes[0] / 3;

  // clamp hist block count to available workspace (grid-stride handles any nbh)
  long long avail = (long long)(ws_size / 4) - PART_OFF;
  int nbh = (int)(avail / PSTRIDE);
  if (nbh > NBH_MAX) nbh = NBH_MAX;
  if (nbh < 128)     nbh = 128;   // i32-sum overflow-safe floor

  hist_kernel<<<nbh+1, 256, 0, stream>>>(x, ehr_w, ehr_b, bio_w, bio_b,
      bio_qkv_w, bio_qkv_b, ehr_qkv_w, ehr_qkv_b,
      attn_in_w, attn_in_b, attn_out_w, attn_out_b,
      ab_proj_w, ab_proj_b, f1_w, f1_b, ws, partials, B, nbh);
  reduce_kernel<<<7*NG, 256, 0, stream>>>(partials, stage2, nbh);
  mid_kernel<<<1, 256, 0, stream>>>(stage2, ws, wsu, bn_g, bn_b, f2_w, B);
  apply_kernel<<<(B + 1023)/1024, 256, 0, stream>>>(x, ws, wsu, f2_b, out, B);
}

// Round 19
// 71.862 us; speedup vs baseline: 2.1602x; 1.0037x over previous
//
#include <hip/hip_runtime.h>
#include <math.h>

#define NITV 17
#define NCELL (NITV*NITV)        // 289
#define NREP 6                   // hist LDS replicas (i32); 41.6KB -> 3 blocks/CU
#define QS   4096.0f
#define QINV (1.0/4096.0)
#define CELLF 6
#define AGG_N (NCELL*CELLF)      // 1734
#define PSTRIDE 1760
#define NG 16
#define NBH_MAX 768              // 3 blocks/CU * 256 CU

// ws dword-offset layout:
#define RAW_OFF   0
#define THR_OFF   4352
#define F2PK_OFF  4384
#define EVT_OFF   4480  // scaled E-table fp16 [16 g2][17 itv] uint4 (1088 dw)
#define BVT_OFF   5568  // scaled B-table (1088 dw)
#define ST2_OFF   6656  // stage2 i64[NG][PSTRIDE]
#define PART_OFF  62976 // partials i32[nbh][PSTRIDE]

typedef _Float16 h2 __attribute__((ext_vector_type(2)));

#if __has_builtin(__builtin_amdgcn_fdot2)
__device__ __forceinline__ float fdot2f(h2 a, h2 b, float c) {
  return __builtin_amdgcn_fdot2(a, b, c, false);
}
#else
__device__ __forceinline__ float fdot2f(h2 a, h2 b, float c) {
  return fmaf((float)a.x, (float)b.x, fmaf((float)a.y, (float)b.y, c));
}
#endif

// count of sorted t[0..15] strictly less than x (17 outcomes; t[15] fix-up).
__device__ __forceinline__ int bsearch17(const float* t, float x) {
  bool c8 = t[7] < x;
  float s2 = c8 ? t[11] : t[3];
  bool c4 = s2 < x;
  float sa = c8 ? t[13] : t[5];
  float sb = c8 ? t[9]  : t[1];
  float s3 = c4 ? sa : sb;
  bool c2 = s3 < x;
  float v00 = c2 ? t[2]  : t[0];
  float v01 = c2 ? t[6]  : t[4];
  float v10 = c2 ? t[10] : t[8];
  float v11 = c2 ? t[14] : t[12];
  float w0 = c4 ? v01 : v00;
  float w1 = c4 ? v11 : v10;
  float s4 = c8 ? w1 : w0;
  bool c1 = s4 < x;
  int c = (c8?8:0) + (c4?4:0) + (c2?2:0) + (c1?1:0);
  c += (t[15] < x) ? 1 : 0;
  return c;
}

// ------------- Kernel 1: 6x i32 LDS-atomic histogram (NREP=6) + setup block -------------
__global__ void __launch_bounds__(256) hist_kernel(
    const float* __restrict__ x,
    const float* __restrict__ ehr_w, const float* __restrict__ ehr_b,
    const float* __restrict__ bio_w, const float* __restrict__ bio_b,
    const float* __restrict__ bio_qkv_w, const float* __restrict__ bio_qkv_b,
    const float* __restrict__ ehr_qkv_w, const float* __restrict__ ehr_qkv_b,
    const float* __restrict__ attn_in_w, const float* __restrict__ attn_in_b,
    const float* __restrict__ attn_out_w, const float* __restrict__ attn_out_b,
    const float* __restrict__ ab_proj_w, const float* __restrict__ ab_proj_b,
    const float* __restrict__ f1_w, const float* __restrict__ f1_b,
    float* __restrict__ ws, int* __restrict__ partials,
    int B, int nbh)
{
  __shared__ __align__(16) int accS[NREP*AGG_N];   // 41.6 KB; setup reuses as float scratch
  __shared__ float thrS[32];
  __shared__ float mvec[16], uvec[16], vvec[16], cab[16], h0p[64];
  __shared__ float wEx[16], bEx[16], cEx[16], tEx[16];
  __shared__ float wBx[16], bBx[16], cBx[16], tBx[16];
  __shared__ int   rkE[16], rkB[16];
  const int tid = threadIdx.x;

  if ((int)blockIdx.x == nbh) {
    // ---------------- setup-only block: build raw tables once ----------------
    float* S  = (float*)accS;       // needs 4352 floats <= 10404 available
    float* M  = S;
    float* P1 = S + 256;
    float* P2 = S + 512;
    float* Ae = S + 768;
    float* Ab = S + 1024;
    float* G  = S + 1280;
    float* Ge = S + 2304;
    float* Gb = S + 3328;

    {
      int o = tid >> 4, k = tid & 15;
      float s = 0.f;
      for (int j = 0; j < 16; ++j)
        s = fmaf(attn_out_w[o*16+j], attn_in_w[(32+j)*16+k], s);
      M[tid] = s;
    }
    if (tid < 16) {
      float s = attn_out_b[tid];
      for (int j = 0; j < 16; ++j)
        s = fmaf(attn_out_w[tid*16+j], attn_in_b[32+j], s);
      mvec[tid] = s;
    }
    __syncthreads();

    {
      int o = tid >> 4, i = tid & 15;
      float s1 = 0.f, s2 = 0.f;
      for (int t = 0; t < 16; ++t) {
        float mt = M[t*16+i];
        s1 = fmaf(ab_proj_w[o*32+t],    mt, s1);
        s2 = fmaf(ab_proj_w[o*32+16+t], mt, s2);
      }
      P1[tid] = s1; P2[tid] = s2;
    }
    if (tid < 16) {
      float su = mvec[tid], sv = mvec[tid];
      for (int i = 0; i < 16; ++i) {
        float mt = M[tid*16+i];
        su = fmaf(mt, ehr_qkv_b[32+i], su);
        sv = fmaf(mt, bio_qkv_b[32+i], sv);
      }
      uvec[tid] = su; vvec[tid] = sv;
    }
    for (int idx = tid; idx < 1024; idx += 256) {
      int j = idx >> 4, k = idx & 15;
      float s = f1_w[j*32+k];
      for (int i = 0; i < 16; ++i)
        s = fmaf(f1_w[j*32+16+i], M[i*16+k], s);
      G[idx] = s;
    }
    __syncthreads();

    {
      int o = tid >> 4, k = tid & 15;
      float s1 = 0.f, s2 = 0.f;
      for (int i = 0; i < 16; ++i) {
        s1 = fmaf(P1[o*16+i], ehr_qkv_w[(32+i)*16+k], s1);
        s2 = fmaf(P2[o*16+i], bio_qkv_w[(32+i)*16+k], s2);
      }
      Ae[tid] = s1; Ab[tid] = s2;
    }
    if (tid < 16) {
      float s = ab_proj_b[tid];
      for (int t = 0; t < 16; ++t) {
        s = fmaf(ab_proj_w[tid*32+t],    uvec[t], s);
        s = fmaf(ab_proj_w[tid*32+16+t], vvec[t], s);
      }
      cab[tid] = s;
    }
    if (tid < 16) {
      float w = ehr_w[tid], b = ehr_b[tid];
      bool z = (w == 0.0f);
      wEx[tid] = z ? 0.f : w;
      bEx[tid] = z ? 0.f : b;
      cEx[tid] = z ? fmaxf(b, 0.f) : 0.f;
      tEx[tid] = z ? __builtin_inff() : (-b / w);
    } else if (tid < 32) {
      int k = tid - 16;
      float w = bio_w[k], b = bio_b[k];
      bool z = (w == 0.0f);
      wBx[k] = z ? 0.f : w;
      bBx[k] = z ? 0.f : b;
      cBx[k] = z ? fmaxf(b, 0.f) : 0.f;
      tBx[k] = z ? __builtin_inff() : (-b / w);
    }
    __syncthreads();

    for (int idx = tid; idx < 1024; idx += 256) {
      int j = idx >> 4, k = idx & 15;
      float s1 = 0.f, s2 = 0.f;
      for (int i = 0; i < 16; ++i) {
        float g = G[j*16+i];
        s1 = fmaf(g, Ae[i*16+k], s1);
        s2 = fmaf(g, Ab[i*16+k], s2);
      }
      Ge[idx] = s1; Gb[idx] = s2;
    }
    if (tid < 64) {
      float s = f1_b[tid];
      for (int i = 0; i < 16; ++i) {
        s = fmaf(G[tid*16+i], cab[i], s);
        s = fmaf(f1_w[tid*32+16+i], mvec[i], s);
      }
      h0p[tid] = s;
    }
    if (tid < 16) {
      int r = 0;
      for (int j = 0; j < 16; ++j)
        r += (tEx[j] < tEx[tid]) || (tEx[j] == tEx[tid] && j < tid);
      rkE[tid] = r;
    } else if (tid < 32) {
      int k = tid - 16, r = 0;
      for (int j = 0; j < 16; ++j)
        r += (tBx[j] < tBx[k]) || (tBx[j] == tBx[k] && j < k);
      rkB[k] = r;
    }
    __syncthreads();

    if (tid < 64) {
      float s = h0p[tid];
      for (int k = 0; k < 16; ++k)
        s += Ge[tid*16+k]*cEx[k] + Gb[tid*16+k]*cBx[k];
      h0p[tid] = s;
    }
    __syncthreads();

    for (int idx = tid; idx < NITV*64; idx += 256) {
      int i = idx >> 6, j = idx & 63;
      float ue = 0.f, ve = 0.f, ub = 0.f, vb = 0.f;
      for (int k = 0; k < 16; ++k) {
        bool actE = (wEx[k] > 0.f) ? (rkE[k] < i) : (rkE[k] >= i);
        bool actB = (wBx[k] > 0.f) ? (rkB[k] < i) : (rkB[k] >= i);
        if (actE) { ue = fmaf(Ge[j*16+k], wEx[k], ue); ve = fmaf(Ge[j*16+k], bEx[k], ve); }
        if (actB) { ub = fmaf(Gb[j*16+k], wBx[k], ub); vb = fmaf(Gb[j*16+k], bBx[k], vb); }
      }
      ws[RAW_OFF + idx]        = ue;
      ws[RAW_OFF + 1088 + idx] = ve + h0p[j];
      ws[RAW_OFF + 2176 + idx] = ub;
      ws[RAW_OFF + 3264 + idx] = vb;
    }
    if (tid < 16) {
      ws[THR_OFF + rkE[tid]]      = tEx[tid];
      ws[THR_OFF + 16 + rkB[tid]] = tBx[tid];
    }
    return;
  }

  // ---------------- histogram path ----------------
  if (tid < 16) {
    float tloc[16];
    #pragma unroll
    for (int j = 0; j < 16; ++j) {
      float w = ehr_w[j], b = ehr_b[j];
      tloc[j] = (w == 0.0f) ? __builtin_inff() : (-b / w);
    }
    float mine = tloc[tid];
    int r = 0;
    #pragma unroll
    for (int j = 0; j < 16; ++j)
      r += (tloc[j] < mine) || (tloc[j] == mine && j < tid);
    thrS[r] = mine;
  } else if (tid < 32) {
    int k = tid - 16;
    float tloc[16];
    #pragma unroll
    for (int j = 0; j < 16; ++j) {
      float w = bio_w[j], b = bio_b[j];
      tloc[j] = (w == 0.0f) ? __builtin_inff() : (-b / w);
    }
    float mine = tloc[k];
    int r = 0;
    #pragma unroll
    for (int j = 0; j < 16; ++j)
      r += (tloc[j] < mine) || (tloc[j] == mine && j < k);
    thrS[16 + r] = mine;
  }
  {
    int4 z4 = make_int4(0,0,0,0);
    int4* a4 = (int4*)accS;
    for (int i = tid; i < (NREP*AGG_N)/4; i += 256) a4[i] = z4;  // 10404/4 = 2601
  }
  __syncthreads();

  float te[16], tb[16];
  #pragma unroll
  for (int k = 0; k < 16; ++k) { te[k] = thrS[k]; tb[k] = thrS[16+k]; }
  const int rep = tid % NREP;
  int* const base = &accS[rep*AGG_N];
  const int i4max = (B + 3) >> 2;

  for (int i4 = blockIdx.x*256 + tid; i4 < i4max; i4 += nbh*256) {
    const int s0 = i4*4;
    float xs0[4], xs2[4];
    int nv = 0;
    if (s0 + 4 <= B) {
      const float4* xp = (const float4*)(x + (size_t)s0*3);
      float4 a = xp[0], b = xp[1], c = xp[2];
      xs0[0]=a.x; xs2[0]=a.z;  xs0[1]=a.w; xs2[1]=b.y;
      xs0[2]=b.z; xs2[2]=c.x;  xs0[3]=c.y; xs2[3]=c.w;
      nv = 4;
    } else {
      for (int u = 0; u < 4; ++u) {
        int i = s0 + u;
        if (i < B) { xs0[nv] = x[3*(size_t)i]; xs2[nv] = x[3*(size_t)i+2]; ++nv; }
      }
    }
    for (int u = 0; u < nv; ++u) {
      float x0 = xs0[u], x2 = xs2[u];
      int iv0 = bsearch17(te, x0);
      int iv2 = bsearch17(tb, x2);
      int* c = base + (iv0*NITV + iv2)*CELLF;
      atomicAdd(c+0, 1);
      atomicAdd(c+1, __float2int_rn(x0*QS));
      atomicAdd(c+2, __float2int_rn(x2*QS));
      atomicAdd(c+3, __float2int_rn(x0*x0*QS));
      atomicAdd(c+4, __float2int_rn(x2*x2*QS));
      atomicAdd(c+5, __float2int_rn(x0*x2*QS));
    }
  }
  __syncthreads();
  // per-block partial: plain coalesced store, no global atomics
  int* out = partials + (size_t)blockIdx.x*PSTRIDE;
  for (int i = tid; i < AGG_N; i += 256) {
    int s = 0;
    #pragma unroll
    for (int r = 0; r < NREP; ++r) s += accS[r*AGG_N + i];
    out[i] = s;
  }
}

// ------------- Kernel 1b: deterministic tree reduce: partials -> stage2 i64 -------------
__global__ void __launch_bounds__(256) reduce_kernel(
    const int* __restrict__ partials, long long* __restrict__ stage2, int nbh)
{
  const int c = blockIdx.x % 7, g = blockIdx.x / 7;
  const int f = c*256 + threadIdx.x;
  if (f >= AGG_N) { if (f < PSTRIDE) stage2[(size_t)g*PSTRIDE + f] = 0; return; }
  long long s = 0;
  for (int b = g; b < nbh; b += NG)          // fixed order per g -> deterministic
    s += (long long)partials[(size_t)b*PSTRIDE + f];
  stage2[(size_t)g*PSTRIDE + f] = s;
}

// ------------- Kernel 2: finalize once -> scaled fp16 uint4 pair-group tables -------------
__global__ void __launch_bounds__(256) mid_kernel(
    const long long* __restrict__ stage2,
    float* ws, unsigned int* wsu,
    const float* __restrict__ bn_g, const float* __restrict__ bn_b,
    const float* __restrict__ f2_w, int B)
{
  __shared__ double aggd[AGG_N];               // 13.9 KB
  __shared__ float  Rl[4352];                  // 17.4 KB
  __shared__ double sh2p[256];                 // 2 KB
  __shared__ double margnE[NITV], margxE[NITV], margnB[NITV], margxB[NITV];
  __shared__ float  sArr[64], aE[64], aB[64];
  const int tid = threadIdx.x;

  for (int i = tid; i < 1088; i += 256)
    ((uint4*)Rl)[i] = ((const uint4*)(ws + RAW_OFF))[i];
  for (int i = tid; i < AGG_N; i += 256) {
    long long v = 0;
    #pragma unroll
    for (int g = 0; g < NG; ++g) v += stage2[(size_t)g*PSTRIDE + i];
    aggd[i] = (i % CELLF == 0) ? (double)v : (double)v * QINV;
  }
  __syncthreads();

  // marginals from joint
  if (tid < NITV) {
    double n = 0, sx = 0;
    for (int q = 0; q < NITV; ++q) {
      n  += aggd[(tid*NITV+q)*CELLF];
      sx += aggd[(tid*NITV+q)*CELLF + 1];
    }
    margnE[tid] = n; margxE[tid] = sx;
  } else if (tid >= 32 && tid < 32+NITV) {
    int q = tid - 32;
    double n = 0, sx = 0;
    for (int p = 0; p < NITV; ++p) {
      n  += aggd[(p*NITV+q)*CELLF];
      sx += aggd[(p*NITV+q)*CELLF + 2];
    }
    margnB[q] = n; margxB[q] = sx;
  }

  // E[h^2]*B, striped over p by 4 wave-groups
  {
    const int j = tid & 63, pg = tid >> 6;
    double sh2 = 0;
    for (int p = pg; p < NITV; p += 4) {
      const double Ue = (double)Rl[p*64+j];
      const double Ve = (double)Rl[1088 + p*64+j];
      for (int q = 0; q < NITV; ++q) {
        const double* c = &aggd[(p*NITV+q)*CELLF];
        double n = c[0], sx0 = c[1], sx2 = c[2], s00 = c[3], s22 = c[4], s02 = c[5];
        double Ub = (double)Rl[2176 + q*64+j];
        double Vb = (double)Rl[3264 + q*64+j];
        sh2 += s00*Ue*Ue + 2.0*sx0*Ue*Ve + n*Ve*Ve
             + s22*Ub*Ub + 2.0*sx2*Ub*Vb + n*Vb*Vb
             + 2.0*(s02*Ue*Ub + sx0*Ue*Vb + sx2*Ve*Ub + n*Ve*Vb);
      }
    }
    sh2p[tid] = sh2;
  }
  __syncthreads();

  if (tid < 64) {
    const int j = tid;
    double sh2 = (sh2p[j] + sh2p[64+j]) + (sh2p[128+j] + sh2p[192+j]);
    const double invB = 1.0 / (double)B;
    double mua = 0, mub = 0;
    for (int p = 0; p < NITV; ++p) {
      mua += margxE[p]*(double)Rl[p*64+j]      + margnE[p]*(double)Rl[1088+p*64+j];
      mub += margxB[p]*(double)Rl[2176+p*64+j] + margnB[p]*(double)Rl[3264+p*64+j];
    }
    mua *= invB; mub *= invB;
    double mu  = mua + mub;
    double var = sh2*invB - mu*mu;
    double s   = (double)bn_g[j] / sqrt(var + 1e-5);
    sArr[j] = (float)s;
    aE[j] = (float)(0.5*(double)bn_b[j] - s*mua);   // split centers keep V small for fp16
    aB[j] = (float)(0.5*(double)bn_b[j] - s*mub);
  }
  __syncthreads();

  // pack scaled fp16 tables: [g2 (16)][itv (17)] uint4 = {U_p0, V_p0, U_p1, V_p1}
  for (int idx = tid; idx < NITV*16; idx += 256) {
    int itv = idx >> 4, g2 = idx & 15;
    int j0 = 4*g2;
    h2 U0, V0, U1, V1;
    // E table
    U0.x = (_Float16)(sArr[j0+0] * Rl[itv*64+j0+0]);
    U0.y = (_Float16)(sArr[j0+1] * Rl[itv*64+j0+1]);
    V0.x = (_Float16)(fmaf(sArr[j0+0], Rl[1088+itv*64+j0+0], aE[j0+0]));
    V0.y = (_Float16)(fmaf(sArr[j0+1], Rl[1088+itv*64+j0+1], aE[j0+1]));
    U1.x = (_Float16)(sArr[j0+2] * Rl[itv*64+j0+2]);
    U1.y = (_Float16)(sArr[j0+3] * Rl[itv*64+j0+3]);
    V1.x = (_Float16)(fmaf(sArr[j0+2], Rl[1088+itv*64+j0+2], aE[j0+2]));
    V1.y = (_Float16)(fmaf(sArr[j0+3], Rl[1088+itv*64+j0+3], aE[j0+3]));
    int base = EVT_OFF + g2*68 + itv*4;
    wsu[base+0] = __builtin_bit_cast(unsigned int, U0);
    wsu[base+1] = __builtin_bit_cast(unsigned int, V0);
    wsu[base+2] = __builtin_bit_cast(unsigned int, U1);
    wsu[base+3] = __builtin_bit_cast(unsigned int, V1);
    // B table
    U0.x = (_Float16)(sArr[j0+0] * Rl[2176+itv*64+j0+0]);
    U0.y = (_Float16)(sArr[j0+1] * Rl[2176+itv*64+j0+1]);
    V0.x = (_Float16)(fmaf(sArr[j0+0], Rl[3264+itv*64+j0+0], aB[j0+0]));
    V0.y = (_Float16)(fmaf(sArr[j0+1], Rl[3264+itv*64+j0+1], aB[j0+1]));
    U1.x = (_Float16)(sArr[j0+2] * Rl[2176+itv*64+j0+2]);
    U1.y = (_Float16)(sArr[j0+3] * Rl[2176+itv*64+j0+3]);
    V1.x = (_Float16)(fmaf(sArr[j0+2], Rl[3264+itv*64+j0+2], aB[j0+2]));
    V1.y = (_Float16)(fmaf(sArr[j0+3], Rl[3264+itv*64+j0+3], aB[j0+3]));
    base = BVT_OFF + g2*68 + itv*4;
    wsu[base+0] = __builtin_bit_cast(unsigned int, U0);
    wsu[base+1] = __builtin_bit_cast(unsigned int, V0);
    wsu[base+2] = __builtin_bit_cast(unsigned int, U1);
    wsu[base+3] = __builtin_bit_cast(unsigned int, V1);
  }
  if (tid < 96) {
    int c = tid >> 5, p = tid & 31;
    h2 F;
    F.x = (_Float16)f2_w[c*64 + 2*p];
    F.y = (_Float16)f2_w[c*64 + 2*p + 1];
    wsu[F2PK_OFF + tid] = __builtin_bit_cast(unsigned int, F);
  }
}

// ------------- Kernel 3: apply (fp16 packed, b128 pair-group reads) -------------
__global__ void __launch_bounds__(256) apply_kernel(
    const float* __restrict__ x, const float* __restrict__ ws,
    const unsigned int* __restrict__ wsu,
    const float* __restrict__ f2_b,
    float* __restrict__ out, int B)
{
  __shared__ __align__(16) unsigned int tabs[2176];   // EVT [0..1088), BVT [1088..2176)
  const int tid = threadIdx.x;

  const int s0 = (blockIdx.x*256 + tid)*4;
  float xs0[4], xs2[4];
  int nv = 0;
  if (s0 + 4 <= B) {
    const float4* xp = (const float4*)(x + (size_t)s0*3);
    float4 a = xp[0], b = xp[1], c = xp[2];
    xs0[0]=a.x; xs2[0]=a.z;  xs0[1]=a.w; xs2[1]=b.y;
    xs0[2]=b.z; xs2[2]=c.x;  xs0[3]=c.y; xs2[3]=c.w;
    nv = 4;
  } else {
    for (int u = 0; u < 4; ++u) {
      int i = s0 + u;
      if (i < B) { xs0[nv] = x[3*(size_t)i]; xs2[nv] = x[3*(size_t)i+2]; ++nv; }
    }
  }

  for (int i = tid; i < 544; i += 256)
    ((uint4*)tabs)[i] = ((const uint4*)(wsu + EVT_OFF))[i];

  float te[16], tb[16];
  #pragma unroll
  for (int k = 0; k < 16; ++k) { te[k] = ws[THR_OFF+k]; tb[k] = ws[THR_OFF+16+k]; }
  const h2* f2h = (const h2*)(wsu + F2PK_OFF);
  const float b0 = f2_b[0], b1 = f2_b[1], b2 = f2_b[2];
  __syncthreads();

  h2 hz; hz.x = (_Float16)0.f; hz.y = (_Float16)0.f;
  float res[12];
  #pragma unroll
  for (int u = 0; u < 4; ++u) {
    if (u >= nv) break;
    float x0 = xs0[u], x2 = xs2[u];
    int iv0 = bsearch17(te, x0);
    int iv2 = bsearch17(tb, x2);
    const uint4* ev4 = ((const uint4*)tabs) + iv0;          // + g2*17
    const uint4* bv4 = ((const uint4*)(tabs + 1088)) + iv2;
    h2 x0h; x0h.x = (_Float16)x0; x0h.y = (_Float16)x0;
    h2 x2h; x2h.x = (_Float16)x2; x2h.y = (_Float16)x2;
    float a0 = b0, a1 = b1, a2 = b2;
    #pragma unroll
    for (int g2 = 0; g2 < 16; ++g2) {
      uint4 e = ev4[g2*NITV];
      uint4 v = bv4[g2*NITV];
      h2 hA0 = __builtin_elementwise_fma(x0h, __builtin_bit_cast(h2, e.x),
                                               __builtin_bit_cast(h2, e.y));
      h2 hB0 = __builtin_elementwise_fma(x2h, __builtin_bit_cast(h2, v.x),
                                               __builtin_bit_cast(h2, v.y));
      h2 r0  = __builtin_elementwise_max(hA0 + hB0, hz);
      h2 hA1 = __builtin_elementwise_fma(x0h, __builtin_bit_cast(h2, e.z),
                                               __builtin_bit_cast(h2, e.w));
      h2 hB1 = __builtin_elementwise_fma(x2h, __builtin_bit_cast(h2, v.z),
                                               __builtin_bit_cast(h2, v.w));
      h2 r1  = __builtin_elementwise_max(hA1 + hB1, hz);
      const int p0 = 2*g2, p1 = 2*g2 + 1;
      a0 = fdot2f(r0, f2h[p0],      fdot2f(r1, f2h[p1],      a0));
      a1 = fdot2f(r0, f2h[32 + p0], fdot2f(r1, f2h[32 + p1], a1));
      a2 = fdot2f(r0, f2h[64 + p0], fdot2f(r1, f2h[64 + p1], a2));
    }
    res[u*3+0] = a0; res[u*3+1] = a1; res[u*3+2] = a2;
  }
  if (nv == 4) {
    float4* op = (float4*)(out + (size_t)s0*3);
    op[0] = make_float4(res[0], res[1], res[2],  res[3]);
    op[1] = make_float4(res[4], res[5], res[6],  res[7]);
    op[2] = make_float4(res[8], res[9], res[10], res[11]);
  } else {
    for (int u = 0; u < nv; ++u) {
      size_t i = (size_t)(s0 + u);
      out[3*i+0] = res[u*3+0]; out[3*i+1] = res[u*3+1]; out[3*i+2] = res[u*3+2];
    }
  }
}

extern "C" void kernel_launch(void* const* d_in, const int* in_sizes, int n_in,
                              void* d_out, int out_size, void* d_ws, size_t ws_size,
                              hipStream_t stream) {
  const float* x          = (const float*)d_in[0];
  const float* ehr_w      = (const float*)d_in[1];
  const float* ehr_b      = (const float*)d_in[2];
  const float* bio_w      = (const float*)d_in[5];
  const float* bio_b      = (const float*)d_in[6];
  const float* bio_qkv_w  = (const float*)d_in[7];
  const float* bio_qkv_b  = (const float*)d_in[8];
  const float* ehr_qkv_w  = (const float*)d_in[9];
  const float* ehr_qkv_b  = (const float*)d_in[10];
  const float* attn_in_w  = (const float*)d_in[13];
  const float* attn_in_b  = (const float*)d_in[14];
  const float* attn_out_w = (const float*)d_in[15];
  const float* attn_out_b = (const float*)d_in[16];
  const float* ab_proj_w  = (const float*)d_in[17];
  const float* ab_proj_b  = (const float*)d_in[18];
  const float* f1_w       = (const float*)d_in[19];
  const float* f1_b       = (const float*)d_in[20];
  const float* bn_g       = (const float*)d_in[21];
  const float* bn_b       = (const float*)d_in[22];
  const float* f2_w       = (const float*)d_in[23];
  const float* f2_b       = (const float*)d_in[24];
  float* out = (float*)d_out;
  float* ws  = (float*)d_ws;
  unsigned int* wsu = (unsigned int*)d_ws;
  int* partials = (int*)d_ws + PART_OFF;
  long long* stage2 = (long long*)((int*)d_ws + ST2_OFF);
  const int B = in_sizes[0] / 3;

  // clamp hist block count to available workspace (grid-stride handles any nbh)
  long long avail = (long long)(ws_size / 4) - PART_OFF;
  int nbh = (int)(avail / PSTRIDE);
  if (nbh > NBH_MAX) nbh = NBH_MAX;
  if (nbh < 128)     nbh = 128;   // i32-sum overflow-safe floor

  hist_kernel<<<nbh+1, 256, 0, stream>>>(x, ehr_w, ehr_b, bio_w, bio_b,
      bio_qkv_w, bio_qkv_b, ehr_qkv_w, ehr_qkv_b,
      attn_in_w, attn_in_b, attn_out_w, attn_out_b,
      ab_proj_w, ab_proj_b, f1_w, f1_b, ws, partials, B, nbh);
  reduce_kernel<<<7*NG, 256, 0, stream>>>(partials, stage2, nbh);
  mid_kernel<<<1, 256, 0, stream>>>(stage2, ws, wsu, bn_g, bn_b, f2_w, B);
  apply_kernel<<<(B + 1023)/1024, 256, 0, stream>>>(x, ws, wsu, f2_b, out, B);
}